// Round 12
// baseline (371.360 us; speedup 1.0000x reference)
//
#include <hip/hip_runtime.h>

// 2D acoustic FDTD, trapezoid temporal blocking (W=8), QB=16 chains.
// 128 phys blocks; worker iff (p&7)<4: b=p&7, q=p>>3 (chain neighbors at
// Delta-p=8 share an XCD/L2 under observed dispatch - R8/R10-proven fast).
// Exchange protocol (R10-proven SOUND): DUAL STORE + DUAL FLAG, NO FENCES,
// decided PER EXCHANGE by dual-poll:
//   data: normal float4 stores (shared-L2 path)  AND  agent-atomic 8B
//         mirror (L3 path). Barrier drains both.
//   flags: plain store (L2) + relaxed agent-atomic (L3).
//   consumer: bounded poll of both; fast wake -> sc0 16B reads (L2);
//             slow wake -> agent-atomic 8B reads (L3). Never hangs, and
//             stale-cached fast flags are harmless (slow flag wins race).
// L/R stencil neighbors via __shfl (conflict-free, R6-proven); vertical in
// registers. Output layout: y[t, r, b] = t*R*B + r*B + b.

constexpr int B_   = 4;
constexpr int NY   = 256;
constexpr int NX   = 256;
constexpr int NT   = 300;
constexpr int RCV  = 128;

constexpr int QB   = 16;               // blocks per batch (chain length)
constexpr int RB   = NY / QB;          // 16 own rows
constexpr int W    = 8;                // temporal depth / halo width
constexpr int EXT  = RB + 2 * W;       // 32 ext rows
constexpr int GRIDB= 128;              // 64 workers + 64 dummies
constexpr int NTHR = 512;              // 8 waves x (4 rows x 256 cols)
constexpr int ROWS = 4;                // ext rows per thread
constexpr int NW   = EXT / ROWS;       // 8 waves
constexpr int SLABR= EXT + 2;          // 34 (+2 zero pads)
constexpr int PUBR = 2 * W - 1;        // 15: rows 0..7 h(T), 8..14 h(T-1)
constexpr int LINKS= B_ * (QB - 1);    // 60
constexpr size_t HALO_FLOATS = (size_t)LINKS * 2 * 2 * PUBR * NX;  // 3.7 MB
constexpr size_t HALO_BYTES  = HALO_FLOATS * sizeof(float);
constexpr int FSTR = 64;               // fast-flag stride (256 B / block)
constexpr size_t CTRL_INTS = (size_t)GRIDB * FSTR + GRIDB;
constexpr int SPIN_LIM = 1 << 20;      // bounded spins: fail loud, not hang

typedef float f32x4 __attribute__((ext_vector_type(4)));

__device__ __forceinline__ void at_store2(float* p, float a, float b) {
    float2 v = make_float2(a, b);
    unsigned long long u;
    __builtin_memcpy(&u, &v, 8);
    __hip_atomic_store((unsigned long long*)p, u, __ATOMIC_RELAXED,
                       __HIP_MEMORY_SCOPE_AGENT);
}
__device__ __forceinline__ float2 at_load2(const float* p) {
    unsigned long long u = __hip_atomic_load((const unsigned long long*)p,
                                             __ATOMIC_RELAXED,
                                             __HIP_MEMORY_SCOPE_AGENT);
    float2 v;
    __builtin_memcpy(&v, &u, 8);
    return v;
}
__device__ __forceinline__ int ld_flag_sc0(const int* p) {
    int v;
    asm volatile("global_load_dword %0, %1, off sc0\n\ts_waitcnt vmcnt(0)"
                 : "=v"(v) : "v"(p) : "memory");
    return v;
}
// dual publish: shared-L2 copy (normal) + L3 copy (agent atomics)
__device__ __forceinline__ void pub2(float* dst, const float v[4]) {
    *reinterpret_cast<float4*>(dst) = make_float4(v[0], v[1], v[2], v[3]);
    at_store2(dst, v[0], v[1]);
    at_store2(dst + 2, v[2], v[3]);
}
// ingest: fast = sc0 16B from shared L2; slow = agent 8B from L3
__device__ __forceinline__ void ing2(const float* src, float v[4], bool fast) {
    if (fast) {
        f32x4 t;
        asm volatile("global_load_dwordx4 %0, %1, off sc0\n\ts_waitcnt vmcnt(0)"
                     : "=v"(t) : "v"(src) : "memory");
        v[0] = t.x; v[1] = t.y; v[2] = t.z; v[3] = t.w;
    } else {
        float2 a = at_load2(src), b2 = at_load2(src + 2);
        v[0] = a.x; v[1] = a.y; v[2] = b2.x; v[3] = b2.y;
    }
}
// bounded dual wait: true -> fast path (shared L2 live for this link NOW)
__device__ __forceinline__ bool dual_wait(const int* fastp, const int* slowp,
                                          int tgt) {
    int g = 0;
    for (;;) {
        if (ld_flag_sc0(fastp) >= tgt) return true;
        if (__hip_atomic_load(slowp, __ATOMIC_RELAXED,
                              __HIP_MEMORY_SCOPE_AGENT) >= tgt) return false;
        if (++g > SPIN_LIM) return false;      // fail loud, never hang
        __builtin_amdgcn_s_sleep(1);
    }
}

__global__ __launch_bounds__(NTHR, 1)
void wave_df2(const float* __restrict__ x,      // B x NT
              const float* __restrict__ vp,     // NY x NX
              const int*   __restrict__ src_y,  // B
              const int*   __restrict__ src_x,  // B
              const int*   __restrict__ rec_y,  // R
              const int*   __restrict__ rec_x,  // R
              float*       __restrict__ y,      // NT x R x B
              float*       __restrict__ halo,   // flag-gated (not zeroed)
              int*         __restrict__ ctrl)   // zeroed flags
{
    const int blk = blockIdx.x;
    const int b = blk & 7;
    if (b >= B_) return;                  // dummies keep chains XCD-local
    const int q = blk >> 3;

    __shared__ float slabs[2][SLABR][NX]; // slot t&1 = h(t); rows 0,33 stay 0

    const int tid = threadIdx.x;
    const int r0 = q * RB;
    const int w = tid >> 6, lane = tid & 63;
    const int c0 = lane * 4;
    const int e0 = ROWS * w;

    int* fastf = ctrl;                    // [GRIDB*FSTR] 256B apart
    int* slowf = ctrl + GRIDB * FSTR;     // [GRIDB]

    for (int i = tid; i < 2 * SLABR * NX; i += NTHR) ((float*)slabs)[i] = 0.f;

    const float scale = 1e-8f;            // dt^2/dx^2
    float hA[ROWS][4], hB[ROWS][4], c2[ROWS][4];
#pragma unroll
    for (int rr = 0; rr < ROWS; ++rr) {
        const int gr = r0 - W + e0 + rr;
        if (gr >= 0 && gr < NY) {
            float4 v = *reinterpret_cast<const float4*>(&vp[gr * NX + c0]);
            c2[rr][0] = v.x * v.x * scale; c2[rr][1] = v.y * v.y * scale;
            c2[rr][2] = v.z * v.z * scale; c2[rr][3] = v.w * v.w * scale;
        } else {
#pragma unroll
            for (int j = 0; j < 4; ++j) c2[rr][j] = 0.f;
        }
#pragma unroll
        for (int j = 0; j < 4; ++j) { hA[rr][j] = 0.f; hB[rr][j] = 0.f; }
    }

    const int sy = src_y[b], sx = src_x[b];
    const int es = sy - r0 + W;           // inject into halo replicas too
    const bool src_mine = (es >= e0) && (es < e0 + ROWS) && ((sx >> 2) == lane);
    const int s_j = sx & 3;

    bool rec_mine = false; int rec_addr = 0; float* yp = nullptr;
    if (tid < RCV) {
        const int ry = rec_y[tid], rx = rec_x[tid];
        rec_mine = (ry >= r0) && (ry < r0 + RB);
        rec_addr = (ry - r0 + W + 1) * NX + rx;   // slab rows [9,25)
        yp = y + tid * B_ + b;
    }

    const float* xb = x + b * NT;
    const size_t lnkQ  = (size_t)(b * (QB - 1) + (q < QB - 1 ? q : 0));
    const size_t lnkQm = (size_t)(b * (QB - 1) + (q > 0 ? q - 1 : 0));
    float*       pubDn  = halo + ((lnkQ  * 2 + 0) * 2) * PUBR * NX;  // q<QB-1
    float*       pubUp  = halo + ((lnkQm * 2 + 1) * 2) * PUBR * NX;  // q>0
    const float* ingTop = halo + ((lnkQm * 2 + 0) * 2) * PUBR * NX;  // q>0
    const float* ingBot = halo + ((lnkQ  * 2 + 1) * 2) * PUBR * NX;  // q<QB-1

    __syncthreads();
    int exch = 0;

#define STEP(HO, HN, tt)                                                       \
    {                                                                          \
        const int cur = (tt) & 1, nxt = ((tt) + 1) & 1;                        \
        if ((tt) > 0 && rec_mine)                                              \
            yp[(size_t)((tt) - 1) * RCV * B_] =                                \
                ((const float*)slabs[cur])[rec_addr];                          \
        const float4 u4 = *reinterpret_cast<const float4*>(&slabs[cur][e0][c0]);\
        const float4 d4 = *reinterpret_cast<const float4*>(&slabs[cur][e0+ROWS+1][c0]);\
        const float ua[4] = {u4.x, u4.y, u4.z, u4.w};                          \
        const float da[4] = {d4.x, d4.y, d4.z, d4.w};                          \
        const float xt = xb[tt];                                               \
        _Pragma("unroll")                                                      \
        for (int rr = 0; rr < ROWS; ++rr) {                                    \
            float lv = __shfl_up(HO[rr][3], 1);   if (lane == 0)  lv = 0.f;    \
            float rv = __shfl_down(HO[rr][0], 1); if (lane == 63) rv = 0.f;    \
            _Pragma("unroll")                                                  \
            for (int j = 0; j < 4; ++j) {                                      \
                const float uu = (rr == 0)      ? ua[j] : HO[rr-1][j];         \
                const float dd = (rr == ROWS-1) ? da[j] : HO[rr+1][j];         \
                const float ll = (j == 0) ? lv : HO[rr][j-1];                  \
                const float rr2= (j == 3) ? rv : HO[rr][j+1];                  \
                HN[rr][j] = 2.f*HO[rr][j] - HN[rr][j]                          \
                          + c2[rr][j]*(uu + dd + ll + rr2 - 4.f*HO[rr][j]);    \
            }                                                                  \
        }                                                                      \
        if (src_mine) {                                                        \
            _Pragma("unroll")                                                  \
            for (int rr = 0; rr < ROWS; ++rr)                                  \
                _Pragma("unroll")                                              \
                for (int j = 0; j < 4; ++j)                                    \
                    if (e0 + rr == es && j == s_j) HN[rr][j] += xt;            \
        }                                                                      \
        _Pragma("unroll")                                                      \
        for (int rr = 0; rr < ROWS; ++rr)                                      \
            *reinterpret_cast<float4*>(&slabs[nxt][e0+1+rr][c0]) =             \
                make_float4(HN[rr][0], HN[rr][1], HN[rr][2], HN[rr][3]);       \
        if ((((tt) + 1) & 7) == 0) {                                           \
            ++exch;                                                            \
            const size_t soff = (size_t)(exch & 1) * PUBR * NX;                \
            _Pragma("unroll")                                                  \
            for (int rr = 0; rr < ROWS; ++rr) {                                \
                const int ext = e0 + rr;                                       \
                if (q < QB-1) {                /* bottom pub: ext[16,24) */    \
                    if (ext >= 16 && ext < 24)                                 \
                        pub2(pubDn + soff + (ext-16)*NX + c0, HN[rr]);         \
                    if (ext >= 17 && ext < 24)                                 \
                        pub2(pubDn + soff + (8+ext-17)*NX + c0, HO[rr]);       \
                }                                                              \
                if (q > 0) {                   /* top pub: ext[8,16) */        \
                    if (ext >= 8 && ext < 16)                                  \
                        pub2(pubUp + soff + (ext-8)*NX + c0, HN[rr]);          \
                    if (ext >= 8 && ext < 15)                                  \
                        pub2(pubUp + soff + (8+ext-8)*NX + c0, HO[rr]);        \
                }                                                              \
            }                                                                  \
            __syncthreads();   /* vmcnt drained: both store paths committed */ \
            if (tid == 0) {                                                    \
                ((volatile int*)fastf)[blk * FSTR] = exch;   /* L2 flag */     \
                __hip_atomic_store(&slowf[blk], exch, __ATOMIC_RELAXED,        \
                                   __HIP_MEMORY_SCOPE_AGENT); /* L3 flag */    \
            }                                                                  \
            if (q > 0 && w <= 1) {             /* top ingest: ext[0,8) */      \
                const bool fast = dual_wait(&fastf[(blk-8)*FSTR],              \
                                            &slowf[blk-8], exch);              \
                _Pragma("unroll")                                              \
                for (int rr = 0; rr < ROWS; ++rr) {                            \
                    const int ext = e0 + rr;                                   \
                    if (ext < 8) {                                             \
                        ing2(ingTop + soff + ext*NX + c0, HN[rr], fast);       \
                        *reinterpret_cast<float4*>(&slabs[nxt][ext+1][c0]) =   \
                            make_float4(HN[rr][0],HN[rr][1],HN[rr][2],HN[rr][3]);\
                        if (ext >= 1)                                          \
                            ing2(ingTop + soff + (7+ext)*NX + c0, HO[rr], fast);\
                    }                                                          \
                }                                                              \
            }                                                                  \
            if (q < QB-1 && w >= NW-2) {       /* bottom ingest: ext[24,32) */ \
                const bool fast = dual_wait(&fastf[(blk+8)*FSTR],              \
                                            &slowf[blk+8], exch);              \
                _Pragma("unroll")                                              \
                for (int rr = 0; rr < ROWS; ++rr) {                            \
                    const int ext = e0 + rr;                                   \
                    if (ext >= 24) {                                           \
                        ing2(ingBot + soff + (ext-24)*NX + c0, HN[rr], fast);  \
                        *reinterpret_cast<float4*>(&slabs[nxt][ext+1][c0]) =   \
                            make_float4(HN[rr][0],HN[rr][1],HN[rr][2],HN[rr][3]);\
                        if (ext < 31)                                          \
                            ing2(ingBot + soff + (8+ext-24)*NX + c0, HO[rr], fast);\
                    }                                                          \
                }                                                              \
            }                                                                  \
            __syncthreads();                                                   \
        } else {                                                               \
            __syncthreads();                                                   \
        }                                                                      \
    }

    for (int t = 0; t < NT; t += 2) {
        STEP(hA, hB, t)
        STEP(hB, hA, t + 1)
    }
#undef STEP

    if (rec_mine)
        yp[(size_t)(NT - 1) * RCV * B_] = ((const float*)slabs[0])[rec_addr];
}

extern "C" void kernel_launch(void* const* d_in, const int* in_sizes, int n_in,
                              void* d_out, int out_size, void* d_ws, size_t ws_size,
                              hipStream_t stream) {
    const float* x     = (const float*)d_in[0];
    const float* vp    = (const float*)d_in[1];
    const int*   src_y = (const int*)d_in[2];
    const int*   src_x = (const int*)d_in[3];
    const int*   rec_y = (const int*)d_in[4];
    const int*   rec_x = (const int*)d_in[5];
    float*       y     = (float*)d_out;

    float* halo = (float*)d_ws;
    int*   ctrl = (int*)((char*)d_ws + HALO_BYTES);

    // only flags need zeroing (halo reads are flag-gated, monotonic epochs)
    hipMemsetAsync(ctrl, 0, CTRL_INTS * sizeof(int), stream);

    wave_df2<<<GRIDB, NTHR, 0, stream>>>(x, vp, src_y, src_x, rec_y, rec_x,
                                         y, halo, ctrl);
}

// Round 13
// 301.042 us; speedup vs baseline: 1.2336x; 1.2336x over previous
//
#include <hip/hip_runtime.h>

// 2D acoustic FDTD, trapezoid temporal blocking (W=8), template QB chains.
// 8*QB phys blocks; worker iff (p&7)<4: b=p&7, q=p>>3 (chain neighbors at
// Delta-p=8 share an XCD/L2 under observed dispatch - R8/R10/R12-proven).
// Exchange protocol (R10/R12-proven SOUND): DUAL STORE + DUAL FLAG, no
// fences, decided PER EXCHANGE by dual-poll:
//   data: normal float4 stores (shared-L2) AND agent-atomic 8B mirror (L3).
//   flags: plain store (L2) + relaxed agent-atomic (L3).
//   consumer: bounded poll of both; fast -> sc0 16B reads; slow -> agent 8B.
//   Stale-cached fast flags harmless (slow flag wins). Never hangs.
// L/R stencil neighbors via LDS EDGE ARRAYS (interleaved {L,R} pairs,
// stride-2 lane access = 2-way = conflict-free; no bpermute, no edge masks:
// pad dwords stay 0 = domain boundary). Vertical neighbors in registers,
// wave-boundary rows via b128 slab reads. Host picks QB=32 (128 CUs) if
// d_ws fits, else proven-footprint QB=16. Output: y[t,r,b]=t*R*B+r*B+b.

constexpr int B_   = 4;
constexpr int NY   = 256;
constexpr int NX   = 256;
constexpr int NT   = 300;
constexpr int RCV  = 128;
constexpr int W    = 8;                // temporal depth / halo width
constexpr int NTHR = 512;              // 8 waves
constexpr int PUBR = 2 * W - 1;        // 15: rows 0..7 h(T), 8..14 h(T-1)
constexpr int FSTR = 64;               // fast-flag stride (256 B / block)
constexpr int EW   = 132;              // edge row width (dwords): pad+128+pad
constexpr int SPIN_LIM = 1 << 20;      // bounded spins: fail loud, not hang

typedef float f32x4 __attribute__((ext_vector_type(4)));

__device__ __forceinline__ void at_store2(float* p, float a, float b) {
    float2 v = make_float2(a, b);
    unsigned long long u;
    __builtin_memcpy(&u, &v, 8);
    __hip_atomic_store((unsigned long long*)p, u, __ATOMIC_RELAXED,
                       __HIP_MEMORY_SCOPE_AGENT);
}
__device__ __forceinline__ float2 at_load2(const float* p) {
    unsigned long long u = __hip_atomic_load((const unsigned long long*)p,
                                             __ATOMIC_RELAXED,
                                             __HIP_MEMORY_SCOPE_AGENT);
    float2 v;
    __builtin_memcpy(&v, &u, 8);
    return v;
}
__device__ __forceinline__ int ld_flag_sc0(const int* p) {
    int v;
    asm volatile("global_load_dword %0, %1, off sc0\n\ts_waitcnt vmcnt(0)"
                 : "=v"(v) : "v"(p) : "memory");
    return v;
}
// dual publish: shared-L2 copy (normal) + L3 copy (agent atomics)
__device__ __forceinline__ void pub2(float* dst, const float v[4]) {
    *reinterpret_cast<float4*>(dst) = make_float4(v[0], v[1], v[2], v[3]);
    at_store2(dst, v[0], v[1]);
    at_store2(dst + 2, v[2], v[3]);
}
// ingest: fast = sc0 16B from shared L2; slow = agent 8B from L3
__device__ __forceinline__ void ing2(const float* src, float v[4], bool fast) {
    if (fast) {
        f32x4 t;
        asm volatile("global_load_dwordx4 %0, %1, off sc0\n\ts_waitcnt vmcnt(0)"
                     : "=v"(t) : "v"(src) : "memory");
        v[0] = t.x; v[1] = t.y; v[2] = t.z; v[3] = t.w;
    } else {
        float2 a = at_load2(src), b2 = at_load2(src + 2);
        v[0] = a.x; v[1] = a.y; v[2] = b2.x; v[3] = b2.y;
    }
}
// bounded dual wait: true -> fast path (shared L2 live for this link NOW)
__device__ __forceinline__ bool dual_wait(const int* fastp, const int* slowp,
                                          int tgt) {
    int g = 0;
    for (;;) {
        if (ld_flag_sc0(fastp) >= tgt) return true;
        if (__hip_atomic_load(slowp, __ATOMIC_RELAXED,
                              __HIP_MEMORY_SCOPE_AGENT) >= tgt) return false;
        if (++g > SPIN_LIM) return false;      // fail loud, never hang
        __builtin_amdgcn_s_sleep(1);
    }
}

template<int QB>
__global__ __launch_bounds__(NTHR, 1)
void wave_k(const float* __restrict__ x,      // B x NT
            const float* __restrict__ vp,     // NY x NX
            const int*   __restrict__ src_y,  // B
            const int*   __restrict__ src_x,  // B
            const int*   __restrict__ rec_y,  // R
            const int*   __restrict__ rec_x,  // R
            float*       __restrict__ y,      // NT x R x B
            float*       __restrict__ halo,   // flag-gated (not zeroed)
            int*         __restrict__ ctrl)   // zeroed flags
{
    constexpr int RB    = NY / QB;            // own rows
    constexpr int EXT   = RB + 2 * W;         // ext rows
    constexpr int ROWS  = EXT / 8;            // rows per thread (8 waves)
    constexpr int SLABR = EXT + 2;            // +2 zero pads
    constexpr int GRIDB = 8 * QB;

    const int blk = blockIdx.x;
    const int b = blk & 7;
    if (b >= B_) return;                      // dummies keep chains XCD-local
    const int q = blk >> 3;

    __shared__ float slabs[2][SLABR][NX];     // slot t&1 = h(t)
    __shared__ float edge[EXT][EW];           // {pad, L0,R0, .., L63,R63, pad}

    const int tid = threadIdx.x;
    const int r0 = q * RB;
    const int w = tid >> 6, lane = tid & 63;
    const int c0 = lane * 4;
    const int e0 = ROWS * w;

    int* fastf = ctrl;                        // [GRIDB*FSTR] 256B apart
    int* slowf = ctrl + GRIDB * FSTR;         // [GRIDB]

    for (int i = tid; i < 2 * SLABR * NX; i += NTHR) ((float*)slabs)[i] = 0.f;
    for (int i = tid; i < EXT * EW; i += NTHR) ((float*)edge)[i] = 0.f;

    const float scale = 1e-8f;                // dt^2/dx^2
    float hA[ROWS][4], hB[ROWS][4], c2[ROWS][4];
#pragma unroll
    for (int rr = 0; rr < ROWS; ++rr) {
        const int gr = r0 - W + e0 + rr;
        if (gr >= 0 && gr < NY) {
            float4 v = *reinterpret_cast<const float4*>(&vp[gr * NX + c0]);
            c2[rr][0] = v.x * v.x * scale; c2[rr][1] = v.y * v.y * scale;
            c2[rr][2] = v.z * v.z * scale; c2[rr][3] = v.w * v.w * scale;
        } else {
#pragma unroll
            for (int j = 0; j < 4; ++j) c2[rr][j] = 0.f;
        }
#pragma unroll
        for (int j = 0; j < 4; ++j) { hA[rr][j] = 0.f; hB[rr][j] = 0.f; }
    }

    const int sy = src_y[b], sx = src_x[b];
    const int es = sy - r0 + W;               // inject into halo replicas too
    const bool src_mine = (es >= e0) && (es < e0 + ROWS) && ((sx >> 2) == lane);
    const int s_j = sx & 3;

    bool rec_mine = false; int rec_addr = 0; float* yp = nullptr;
    if (tid < RCV) {
        const int ry = rec_y[tid], rx = rec_x[tid];
        rec_mine = (ry >= r0) && (ry < r0 + RB);
        rec_addr = (ry - r0 + W + 1) * NX + rx;
        yp = y + tid * B_ + b;
    }

    const float* xb = x + b * NT;
    const size_t lnkQ  = (size_t)(b * (QB - 1) + (q < QB - 1 ? q : 0));
    const size_t lnkQm = (size_t)(b * (QB - 1) + (q > 0 ? q - 1 : 0));
    float*       pubDn  = halo + ((lnkQ  * 2 + 0) * 2) * PUBR * NX;  // q<QB-1
    float*       pubUp  = halo + ((lnkQm * 2 + 1) * 2) * PUBR * NX;  // q>0
    const float* ingTop = halo + ((lnkQm * 2 + 0) * 2) * PUBR * NX;  // q>0
    const float* ingBot = halo + ((lnkQ  * 2 + 1) * 2) * PUBR * NX;  // q<QB-1

    __syncthreads();
    int exch = 0;

#define STEP(HO, HN, tt)                                                       \
    {                                                                          \
        const int cur = (tt) & 1, nxt = ((tt) + 1) & 1;                        \
        if ((tt) > 0 && rec_mine)                                              \
            yp[(size_t)((tt) - 1) * RCV * B_] =                                \
                ((const float*)slabs[cur])[rec_addr];                          \
        const float4 u4 = *reinterpret_cast<const float4*>(&slabs[cur][e0][c0]);\
        const float4 d4 = *reinterpret_cast<const float4*>(&slabs[cur][e0+ROWS+1][c0]);\
        const float ua[4] = {u4.x, u4.y, u4.z, u4.w};                          \
        const float da[4] = {d4.x, d4.y, d4.z, d4.w};                          \
        float lvv[ROWS], rvv[ROWS];                                            \
        _Pragma("unroll")                                                      \
        for (int rr = 0; rr < ROWS; ++rr) {   /* h(t) edges, conflict-free */  \
            const float* er = &edge[e0 + rr][0];                               \
            lvv[rr] = er[2 * lane];           /* left lane's R (pad0 = 0) */   \
            rvv[rr] = er[2 * lane + 3];       /* right lane's L (pad = 0) */   \
        }                                                                      \
        const float xt = xb[tt];                                               \
        _Pragma("unroll")                                                      \
        for (int rr = 0; rr < ROWS; ++rr) {                                    \
            _Pragma("unroll")                                                  \
            for (int j = 0; j < 4; ++j) {                                      \
                const float uu = (rr == 0)      ? ua[j] : HO[rr-1][j];         \
                const float dd = (rr == ROWS-1) ? da[j] : HO[rr+1][j];         \
                const float ll = (j == 0) ? lvv[rr] : HO[rr][j-1];             \
                const float rr2= (j == 3) ? rvv[rr] : HO[rr][j+1];             \
                HN[rr][j] = 2.f*HO[rr][j] - HN[rr][j]                          \
                          + c2[rr][j]*(uu + dd + ll + rr2 - 4.f*HO[rr][j]);    \
            }                                                                  \
        }                                                                      \
        if (src_mine) {                                                        \
            _Pragma("unroll")                                                  \
            for (int rr = 0; rr < ROWS; ++rr)                                  \
                _Pragma("unroll")                                              \
                for (int j = 0; j < 4; ++j)                                    \
                    if (e0 + rr == es && j == s_j) HN[rr][j] += xt;            \
        }                                                                      \
        _Pragma("unroll")                                                      \
        for (int rr = 0; rr < ROWS; ++rr) {   /* publish h(t+1): slab+edges */ \
            *reinterpret_cast<float4*>(&slabs[nxt][e0+1+rr][c0]) =             \
                make_float4(HN[rr][0], HN[rr][1], HN[rr][2], HN[rr][3]);       \
            edge[e0 + rr][2 * lane + 1] = HN[rr][0];                           \
            edge[e0 + rr][2 * lane + 2] = HN[rr][3];                           \
        }                                                                      \
        if ((((tt) + 1) & 7) == 0) {                                           \
            ++exch;                                                            \
            const size_t soff = (size_t)(exch & 1) * PUBR * NX;                \
            _Pragma("unroll")                                                  \
            for (int rr = 0; rr < ROWS; ++rr) {                                \
                const int ext = e0 + rr;                                       \
                if (q < QB-1) {                /* down pub: own region */      \
                    if (ext >= RB && ext < RB + W)                             \
                        pub2(pubDn + soff + (ext-RB)*NX + c0, HN[rr]);         \
                    if (ext >= RB + 1 && ext < RB + W)                         \
                        pub2(pubDn + soff + (W+ext-RB-1)*NX + c0, HO[rr]);     \
                }                                                              \
                if (q > 0) {                   /* up pub: rows [W,2W) */       \
                    if (ext >= W && ext < 2*W)                                 \
                        pub2(pubUp + soff + (ext-W)*NX + c0, HN[rr]);          \
                    if (ext >= W && ext < 2*W - 1)                             \
                        pub2(pubUp + soff + (W+ext-W)*NX + c0, HO[rr]);        \
                }                                                              \
            }                                                                  \
            __syncthreads();   /* vmcnt drained: both store paths committed */ \
            if (tid == 0) {                                                    \
                ((volatile int*)fastf)[blk * FSTR] = exch;   /* L2 flag */     \
                __hip_atomic_store(&slowf[blk], exch, __ATOMIC_RELAXED,        \
                                   __HIP_MEMORY_SCOPE_AGENT); /* L3 flag */    \
            }                                                                  \
            if (q > 0 && e0 < W) {             /* top ingest: ext[0,W) */      \
                const bool fast = dual_wait(&fastf[(blk-8)*FSTR],              \
                                            &slowf[blk-8], exch);              \
                _Pragma("unroll")                                              \
                for (int rr = 0; rr < ROWS; ++rr) {                            \
                    const int ext = e0 + rr;                                   \
                    if (ext < W) {                                             \
                        ing2(ingTop + soff + ext*NX + c0, HN[rr], fast);       \
                        *reinterpret_cast<float4*>(&slabs[nxt][ext+1][c0]) =   \
                            make_float4(HN[rr][0],HN[rr][1],HN[rr][2],HN[rr][3]);\
                        edge[ext][2*lane+1] = HN[rr][0];                       \
                        edge[ext][2*lane+2] = HN[rr][3];                       \
                        if (ext >= 1)                                          \
                            ing2(ingTop + soff + (W-1+ext)*NX + c0, HO[rr], fast);\
                    }                                                          \
                }                                                              \
            }                                                                  \
            if (q < QB-1 && e0 + ROWS > EXT - W) {  /* bottom ingest */        \
                const bool fast = dual_wait(&fastf[(blk+8)*FSTR],              \
                                            &slowf[blk+8], exch);              \
                _Pragma("unroll")                                              \
                for (int rr = 0; rr < ROWS; ++rr) {                            \
                    const int ext = e0 + rr;                                   \
                    if (ext >= EXT - W) {                                      \
                        ing2(ingBot + soff + (ext-(EXT-W))*NX + c0, HN[rr], fast);\
                        *reinterpret_cast<float4*>(&slabs[nxt][ext+1][c0]) =   \
                            make_float4(HN[rr][0],HN[rr][1],HN[rr][2],HN[rr][3]);\
                        edge[ext][2*lane+1] = HN[rr][0];                       \
                        edge[ext][2*lane+2] = HN[rr][3];                       \
                        if (ext < EXT - 1)                                     \
                            ing2(ingBot + soff + (W+ext-(EXT-W))*NX + c0, HO[rr], fast);\
                    }                                                          \
                }                                                              \
            }                                                                  \
            __syncthreads();                                                   \
        } else {                                                               \
            __syncthreads();                                                   \
        }                                                                      \
    }

    for (int t = 0; t < NT; t += 2) {
        STEP(hA, hB, t)
        STEP(hB, hA, t + 1)
    }
#undef STEP

    if (rec_mine)
        yp[(size_t)(NT - 1) * RCV * B_] = ((const float*)slabs[0])[rec_addr];
}

extern "C" void kernel_launch(void* const* d_in, const int* in_sizes, int n_in,
                              void* d_out, int out_size, void* d_ws, size_t ws_size,
                              hipStream_t stream) {
    const float* x     = (const float*)d_in[0];
    const float* vp    = (const float*)d_in[1];
    const int*   src_y = (const int*)d_in[2];
    const int*   src_x = (const int*)d_in[3];
    const int*   rec_y = (const int*)d_in[4];
    const int*   rec_x = (const int*)d_in[5];
    float*       y     = (float*)d_out;
    float*       halo  = (float*)d_ws;

    // QB=32 footprint: 124 links * 2 dirs * 2 slots * 15 rows * 1KB = 7.62 MB
    constexpr size_t HB32 = (size_t)(B_ * 31) * 2 * 2 * PUBR * NX * sizeof(float);
    constexpr size_t CT32 = ((size_t)256 * FSTR + 256) * sizeof(int);
    constexpr size_t HB16 = (size_t)(B_ * 15) * 2 * 2 * PUBR * NX * sizeof(float);
    constexpr size_t CT16 = ((size_t)128 * FSTR + 128) * sizeof(int);

    if (ws_size >= HB32 + CT32) {          // preferred: 128 CUs, less work each
        int* ctrl = (int*)((char*)d_ws + HB32);
        hipMemsetAsync(ctrl, 0, CT32, stream);
        wave_k<32><<<256, NTHR, 0, stream>>>(x, vp, src_y, src_x, rec_y, rec_x,
                                             y, halo, ctrl);
    } else {                               // proven-footprint fallback
        int* ctrl = (int*)((char*)d_ws + HB16);
        hipMemsetAsync(ctrl, 0, CT16, stream);
        wave_k<16><<<128, NTHR, 0, stream>>>(x, vp, src_y, src_x, rec_y, rec_x,
                                             y, halo, ctrl);
    }
}